// Round 22
// baseline (658.588 us; speedup 1.0000x reference)
//
#include <hip/hip_runtime.h>
#include <hip/hip_bf16.h>

typedef __attribute__((ext_vector_type(4))) float f32x4;
typedef __attribute__((ext_vector_type(8))) short short8;
typedef __attribute__((ext_vector_type(4))) unsigned int u32x4;
typedef __attribute__((ext_vector_type(4))) unsigned short u16x4;

static __device__ __forceinline__ unsigned short f2bf(float f){
  unsigned u = __builtin_bit_cast(unsigned, f);
  u += 0x7FFFu + ((u >> 16) & 1u);
  return (unsigned short)(u >> 16);
}
static __device__ __forceinline__ float bf2f(unsigned short b){
  return __builtin_bit_cast(float, ((unsigned)b) << 16);
}
// float -> OCP e4m3fn (software; one-time cvt kernel + fallback)
static __device__ __forceinline__ unsigned char f2e4m3(float x){
  unsigned u = __builtin_bit_cast(unsigned, x);
  unsigned s = (u >> 24) & 0x80u;
  float ax = __builtin_fabsf(x);
  if (ax < 0.015625f) {
    int q = (int)(ax * 512.f + 0.5f);
    return (unsigned char)(s | (unsigned)q);
  }
  if (ax > 448.f) return (unsigned char)(s | 0x7Eu);
  unsigned v = __builtin_bit_cast(unsigned, ax);
  v += 0x00080000u + ((v >> 20) & 1u);
  if (__builtin_bit_cast(float, v & 0xFFF00000u) > 448.f)
    return (unsigned char)(s | 0x7Eu);
  unsigned ee = ((v >> 23) & 0xFFu) - 127u + 7u;
  unsigned m = (v >> 20) & 7u;
  return (unsigned char)(s | (ee << 3) | m);
}
static __device__ __forceinline__ unsigned char h2fp8(float hx16){
#if __has_builtin(__builtin_amdgcn_cvt_pk_fp8_f32)
  int pk = __builtin_amdgcn_cvt_pk_fp8_f32(hx16, hx16, 0, false);
  return (unsigned char)(pk & 0xFF);
#else
  return f2e4m3(hx16);
#endif
}
static __device__ __forceinline__ f32x4 mfma16(short8 a, short8 b, f32x4 c){
  return __builtin_amdgcn_mfma_f32_16x16x32_bf16(a, b, c, 0, 0, 0);
}
static __device__ __forceinline__ f32x4 mfma8(long a, long b, f32x4 c){
  return __builtin_amdgcn_mfma_f32_16x16x32_fp8_fp8(a, b, c, 0, 0, 0);
}
static __device__ __forceinline__ float rcpf(float x){ return __builtin_amdgcn_rcpf(x); }
static __device__ __forceinline__ float sigf(float x){ return rcpf(1.f + __expf(-x)); }
static __device__ __forceinline__ float tanhfast(float x){
  float e = __expf(2.f*x);
  return (e - 1.f) * rcpf(e + 1.f);
}
// spread C-fragment: lane (l4,l15) takes component l4 of src-lane l15's vec
static __device__ __forceinline__ float spread4(f32x4 v, int l15, int l4){
  float x0 = __shfl(v[0], l15, 64);
  float x1 = __shfl(v[1], l15, 64);
  float x2 = __shfl(v[2], l15, 64);
  float x3 = __shfl(v[3], l15, 64);
  float s01 = (l4 & 1) ? x1 : x0;
  float s23 = (l4 & 1) ? x3 : x2;
  return (l4 & 2) ? s23 : s01;
}

// ---------------------------------------------------------------------------
// fp32 -> bf16 conversion: head_W + emb_text + tok_emb (big) + 4 smalls.
// ---------------------------------------------------------------------------
__global__ __launch_bounds__(256) void k_cvt(
    const float* __restrict__ sh, unsigned short* __restrict__ dh,
    const float* __restrict__ se, unsigned short* __restrict__ de,
    const float* __restrict__ st, unsigned short* __restrict__ dt,
    const float* __restrict__ s0, const float* __restrict__ s1,
    const float* __restrict__ s2, const float* __restrict__ s3,
    unsigned short* __restrict__ d0, unsigned short* __restrict__ d1,
    unsigned short* __restrict__ d2, unsigned short* __restrict__ d3)
{
  const long NH4 = 2048000;   // 8,192,000 floats / 4 (head, emb, tok each)
  const long NS4 = 49152;     // 196,608 floats / 4
  const long total = 3*NH4 + 4*NS4;
  for (long idx = (long)blockIdx.x*blockDim.x + threadIdx.x; idx < total;
       idx += (long)gridDim.x*blockDim.x) {
    const float* s; unsigned short* d; long off;
    if (idx < NH4)        { s = sh; d = dh; off = idx; }
    else if (idx < 2*NH4) { s = se; d = de; off = idx - NH4; }
    else if (idx < 3*NH4) { s = st; d = dt; off = idx - 2*NH4; }
    else {
      long r = idx - 3*NH4; int mat = (int)(r / NS4); off = r - (long)mat*NS4;
      switch (mat) {
        case 0: s=s0; d=d0; break;  case 1: s=s1; d=d1; break;
        case 2: s=s2; d=d2; break;  default: s=s3; d=d3; break;
      }
    }
    f32x4 v = ((const f32x4*)s)[off];
    u16x4 o2;
    o2[0]=f2bf(v[0]); o2[1]=f2bf(v[1]); o2[2]=f2bf(v[2]); o2[3]=f2bf(v[3]);
    ((u16x4*)d)[off] = o2;
  }
}

// ---------------------------------------------------------------------------
// Whh -> fp8 e4m3 x16 FRAG-MAJOR, ALL THREE GATES (for the all-fp8 k_gru):
//   byte off ((w*3+g)*8+kb)*512 + lane*8 ;
//   row = g*256 + w*16 + (lane&15), k0 = kb*32 + (lane>>4)*8.  192KB/mat.
// ---------------------------------------------------------------------------
__global__ __launch_bounds__(256) void k_cvtw(
    const float* __restrict__ s0, const float* __restrict__ s1,
    const float* __restrict__ s2,
    unsigned char* __restrict__ z0, unsigned char* __restrict__ z1,
    unsigned char* __restrict__ z2)
{
  int idx = blockIdx.x*256 + threadIdx.x;     // 3 mats x 24576 8B-chunks
  if (idx >= 3*24576) return;
  int mat = idx / 24576, c = idx % 24576;
  const float* s = (mat==0) ? s0 : (mat==1 ? s1 : s2);
  unsigned char* d = (mat==0) ? z0 : (mat==1 ? z1 : z2);
  int lane = c & 63;
  int rest = c >> 6;          // 0..383
  int kb = rest & 7;
  int wg = rest >> 3;         // 0..47
  int g = wg % 3, w = wg / 3;
  int row = g*256 + w*16 + (lane & 15);
  int k0  = kb*32 + (lane >> 4)*8;
  const float* sp = s + (long)row*256 + k0;
  f32x4 a = *(const f32x4*)sp;
  f32x4 b = *(const f32x4*)(sp + 4);
  unsigned char ob[8];
  ob[0]=f2e4m3(a[0]*16.f); ob[1]=f2e4m3(a[1]*16.f);
  ob[2]=f2e4m3(a[2]*16.f); ob[3]=f2e4m3(a[3]*16.f);
  ob[4]=f2e4m3(b[0]*16.f); ob[5]=f2e4m3(b[1]*16.f);
  ob[6]=f2e4m3(b[2]*16.f); ob[7]=f2e4m3(b[3]*16.f);
  unsigned lo = (unsigned)ob[0] | ((unsigned)ob[1]<<8) |
                ((unsigned)ob[2]<<16) | ((unsigned)ob[3]<<24);
  unsigned hi = (unsigned)ob[4] | ((unsigned)ob[5]<<8) |
                ((unsigned)ob[6]<<16) | ((unsigned)ob[7]<<24);
  *(unsigned*)(d + (long)c*8)     = lo;
  *(unsigned*)(d + (long)c*8 + 4) = hi;
}

// ---------------------------------------------------------------------------
// Generic MFMA GEMM: out[M][N] = gatherA[M][Ktot] @ W[N][Ktot]^T + bias
//   AT=0: fp32 A table (with optional concat tabB2); AT=1: bf16 A table.
// ---------------------------------------------------------------------------
template<int TN, int TS, int EPI, int AT>
__global__ __launch_bounds__(256) void k_gemm(
    const void* __restrict__ tabA_, int ldA,
    const float* __restrict__ tabB2, int ldB2, int K1,
    const int* __restrict__ ids,
    const unsigned short* __restrict__ W,   // [N][Ktot] bf16
    const float* __restrict__ bias,         // [N]
    int M, int Ktot,
    void* __restrict__ outp, int ldOut)
{
  const int bm = blockIdx.x, bn = blockIdx.y;
  const int tid = threadIdx.x;
  const int lane = tid & 63, w = tid >> 6;
  const int l15 = lane & 15, l4 = lane >> 4;

  const int r_g = bm*64 + w*16 + l15;
  const int r_c = (r_g < M) ? r_g : (M-1);
  long row_src;
  if (ids) { int ii = (r_c / TN) * TS + (r_c % TN); row_src = ids[ii]; }
  else row_src = r_c;

  const int kchunk = l4 * 8;
  const int ncol0 = bn*128 + l15;

  f32x4 acc[8];
  #pragma unroll
  for (int i=0;i<8;i++){ f32x4 z4 = {0.f,0.f,0.f,0.f}; acc[i]=z4; }

  const int KB = Ktot >> 5;
  for (int kb = 0; kb < KB; ++kb) {
    int k = kb*32 + kchunk;
    short8 afr;
    if (AT == 1) {
      afr = *(const short8*)((const unsigned short*)tabA_ + row_src*(long)ldA + k);
    } else {
      const float* ap;
      if (tabB2 && k >= K1) ap = tabB2 + row_src*(long)ldB2 + (k - K1);
      else                  ap = (const float*)tabA_ + row_src*(long)ldA + k;
      f32x4 a0 = *(const f32x4*)ap;
      f32x4 a1 = *(const f32x4*)(ap + 4);
      afr[0]=(short)f2bf(a0[0]); afr[1]=(short)f2bf(a0[1]);
      afr[2]=(short)f2bf(a0[2]); afr[3]=(short)f2bf(a0[3]);
      afr[4]=(short)f2bf(a1[0]); afr[5]=(short)f2bf(a1[1]);
      afr[6]=(short)f2bf(a1[2]); afr[7]=(short)f2bf(a1[3]);
    }
    #pragma unroll
    for (int ct=0; ct<8; ++ct) {
      int n = ncol0 + ct*16;
      short8 bfr = *(const short8*)(W + (long)n*Ktot + k);
      acc[ct] = mfma16(afr, bfr, acc[ct]);
    }
  }

  #pragma unroll
  for (int ct=0; ct<8; ++ct) {
    int n = ncol0 + ct*16;
    float bv = bias[n];
    #pragma unroll
    for (int q=0; q<4; ++q) {
      int rr = bm*64 + w*16 + l4*4 + q;
      if (rr < M) {
        float v = acc[ct][q] + bv;
        if (EPI == 1) ((float*)outp)[(long)rr*ldOut + n] = tanhfast(v);
        else ((unsigned short*)outp)[(long)rr*ldOut + n] = f2bf(v);
      }
    }
  }
}

// ---------------------------------------------------------------------------
// GRU recurrence, ROW-SPLIT (4 rows/block) + SHUFFLE-SPREAD + ALL-FP8.
//   R21 = 175us decoder (3310cy/step), MfmaUtil 0.69, VALUBusy 0.57.
//   Per-step MFMA floor is structural (384 MFMAs/CU = ~1860cy); the slack
//   is VALU addressing: three 64-bit xrow*768 chains + outs/mask addr per
//   step, unhoistable past runtime null checks. This round: all per-step
//   addresses become POINTER INCREMENTS hoisted out of the loop (xp+=768,
//   op+=256, mp++, parity-selected LDS write offsets precomputed).
//   Numerics identical to R21.
// ---------------------------------------------------------------------------
__global__ __launch_bounds__(1024, 1) void k_gru(
    const unsigned char*  __restrict__ WF8,  // fp8 all-gate frag-major (k_cvtw)
    const float* __restrict__ bhh,           // [768]
    const unsigned short* __restrict__ xg,   // [(grow*T+t)][768] bf16 (bih inc.)
    const int* __restrict__ mask,            // [(grow*T+t)] or null
    const unsigned short* __restrict__ h0bf, // [16][256] bf16 GLOBAL rows, or null
    float* __restrict__ hNf,                 // [grow][256] f32 or null
    unsigned short* __restrict__ hNbf,       // [16][256] bf16 GLOBAL rows, or null
    unsigned short* __restrict__ outs,       // [(grow*T+t)][256] bf16 or null
    int T)
{
  __shared__ unsigned char h8z[9*264];       // fp8 h(x16): rows0-3=p0,4-7=p1,8=zero

  const int tid = threadIdx.x;
  const int w = tid >> 6, lane = tid & 63;
  const int l15 = lane & 15, l4 = lane >> 4;
  const int rowbase = blockIdx.x * 4;
  const int u = w*16 + l15;                  // this lane's unit
  const int gr = l4;                         // this lane's gate row (0..3)

  // ---- weights: all three gates fp8 -> 24 longs (48 VGPR) ----
  long Bf8[3][8];
  #pragma unroll
  for (int g=0; g<3; ++g)
    #pragma unroll
    for (int kb=0; kb<8; ++kb)
      Bf8[g][kb] = *(const long*)(WF8 + ((long)((w*3+g)*8+kb)*512) + lane*8);

  const float b_r = bhh[u], b_z = bhh[256+u], b_n = bhh[512+u];

  // A-read offsets (parity-selected; tile rows >=4 alias zero-row 8)
  const int arow0 = (l15 < 4) ? l15     : 8;
  const int arow1 = (l15 < 4) ? 4 + l15 : 8;
  const int h8O0 = arow0*264 + l4*8;
  const int h8O1 = arow1*264 + l4*8;
  // parity-selected h write offsets (p=0 writes rows 4-7; p=1 rows 0-3)
  const int wA0 = (4+gr)*264 + u;
  const int wA1 = gr*264 + u;

  // ---- hoisted per-step pointers (this lane's row = rowbase+gr) ----
  const long row0 = (long)(rowbase + gr)*T;
  const unsigned short* xp = xg + row0*768 + u;
  unsigned short* op = outs ? (outs + row0*256 + u) : (unsigned short*)0;
  const int* mp = mask ? (mask + row0) : (const int*)0;

  // ---- init: zero row 8; lane owns (row gr, unit u); exact f32 h ----
  if (tid < 264) h8z[8*264 + tid] = 0;
  float h = h0bf ? bf2f(h0bf[(rowbase+gr)*256 + u]) : 0.f;
  h8z[gr*264 + u] = h2fp8(h * 16.f);
  __syncthreads();

  const float inv256 = 0.00390625f;

  for (int t=0; t<T; ++t) {
    const int p = t & 1;

    // ---- xg prefetch: pointer-relative, no per-step address math ----
    const unsigned short xr_ = xp[0];
    const unsigned short xz_ = xp[256];
    const unsigned short xn_ = xp[512];
    const int mok = mp ? *mp : 1;

    // ---- MFMA: 16 units x 3 gates; A is one b64 fp8 read per kb ----
    const int h8O = p ? h8O1 : h8O0;
    f32x4 aR={0.f,0.f,0.f,0.f}, aZ={0.f,0.f,0.f,0.f}, aN={0.f,0.f,0.f,0.f};
    #pragma unroll
    for (int kb=0; kb<8; ++kb) {
      long a8 = *(const long*)&h8z[h8O + kb*32];
      aR = mfma8(a8, Bf8[0][kb], aR);
      aZ = mfma8(a8, Bf8[1][kb], aZ);
      aN = mfma8(a8, Bf8[2][kb], aN);
    }

    // ---- spread C rows across the wave; ONE gate triple per lane ----
    float gR = spread4(aR, l15, l4) * inv256;
    float gZ = spread4(aZ, l15, l4) * inv256;
    float gN = spread4(aN, l15, l4) * inv256;

    float rr = sigf(bf2f(xr_) + gR + b_r);
    float zz = sigf(bf2f(xz_) + gZ + b_z);
    float nn = tanhfast(bf2f(xn_) + rr*(gN + b_n));
    float hv = nn + zz*(h - nn);
    if (!mok) hv = h;
    h = hv;
    h8z[p ? wA1 : wA0] = h2fp8(hv * 16.f);
    if (op) { *op = f2bf(hv); op += 256; }
    xp += 768;
    if (mp) ++mp;
    __syncthreads();
  }

  if (hNf)  hNf[(long)(rowbase+gr)*256 + u] = h;
  if (hNbf) hNbf[(rowbase+gr)*256 + u] = f2bf(h);
}

// ---------------------------------------------------------------------------
// Memory scan: per batch b (block, 1 wave): 32 steps of attention-write memory.
// ---------------------------------------------------------------------------
__global__ __launch_bounds__(64) void k_mem(
    const float* __restrict__ z,         // [512][256] rows b*32+t
    const float* __restrict__ mem_init,  // [16][256]
    float* __restrict__ z2)              // [512][256]
{
  const int b = blockIdx.x;
  const int lane = threadIdx.x;
  float mem[16][4];
  #pragma unroll
  for (int m=0; m<16; ++m) {
    f32x4 v = *(const f32x4*)(mem_init + m*256 + lane*4);
    mem[m][0]=v[0]; mem[m][1]=v[1]; mem[m][2]=v[2]; mem[m][3]=v[3];
  }
  for (int t=0; t<32; ++t) {
    f32x4 q = *(const f32x4*)(z + ((long)b*32 + t)*256 + lane*4);
    float s[16];
    #pragma unroll
    for (int m=0; m<16; ++m)
      s[m] = mem[m][0]*q[0] + mem[m][1]*q[1] + mem[m][2]*q[2] + mem[m][3]*q[3];
    #pragma unroll
    for (int st=1; st<64; st<<=1) {
      #pragma unroll
      for (int m=0; m<16; ++m) s[m] += __shfl_xor(s[m], st, 64);
    }
    float mx = -1e30f;
    #pragma unroll
    for (int m=0; m<16; ++m) { s[m] *= 0.0625f; mx = fmaxf(mx, s[m]); }
    float sum = 0.f;
    #pragma unroll
    for (int m=0; m<16; ++m) { s[m] = __expf(s[m]-mx); sum += s[m]; }
    float inv = rcpf(sum);
    f32x4 ro = {0.f,0.f,0.f,0.f};
    #pragma unroll
    for (int m=0; m<16; ++m) {
      float wm = s[m]*inv;
      #pragma unroll
      for (int c=0; c<4; ++c) {
        ro[c] += wm * mem[m][c];
        mem[m][c] += wm * (q[c] - mem[m][c]);
      }
    }
    f32x4 o = q + ro;
    *(f32x4*)(z2 + ((long)b*32 + t)*256 + lane*4) = o;
  }
}

// ---------------------------------------------------------------------------
// Head GEMM: out[2032][32000] = A[2032][256]bf16 @ Bw[32000][256]^T + bias
// ---------------------------------------------------------------------------
__global__ __launch_bounds__(256) void k_head(
    const unsigned short* __restrict__ A,    // [2048][256] bf16 (padded)
    const unsigned short* __restrict__ Bw,   // [32000][256] bf16
    const float* __restrict__ bias,          // [32000]
    float* __restrict__ out,                 // [2032][32000]
    int M)
{
  __shared__ unsigned short Bs[32768];       // 64 KB
  const int bid = blockIdx.x;
  const int mt = bid % 16, nt = bid / 16;
  const int tid = threadIdx.x;
  const int lane = tid & 63, w = tid >> 6;
  const int l15 = lane & 15, l4 = lane >> 4;

  const long nbase = (long)nt * 128;
  #pragma unroll
  for (int it=0; it<16; ++it) {
    int idx = it*256 + tid;
    int rr = idx >> 5;
    int ch = idx & 31;
    int sch = ch ^ (rr & 7);
    u32x4 v = *(const u32x4*)(Bw + (nbase+rr)*256 + sch*8);
    *(u32x4*)&Bs[(long)idx*8] = v;
  }
  __syncthreads();

  const int m0 = mt*128 + w*32;
  const int arow0 = m0 + l15, arow1 = arow0 + 16;
  const int kc = l4 * 8;

  f32x4 acc[2][8];
  #pragma unroll
  for (int rt=0; rt<2; ++rt)
    #pragma unroll
    for (int ct=0; ct<8; ++ct){ f32x4 z4={0.f,0.f,0.f,0.f}; acc[rt][ct]=z4; }

  #pragma unroll
  for (int kb=0; kb<8; ++kb) {
    short8 a0 = *(const short8*)(A + (long)arow0*256 + kb*32 + kc);
    short8 a1 = *(const short8*)(A + (long)arow1*256 + kb*32 + kc);
    int c = kb*4 + l4;
    #pragma unroll
    for (int ct=0; ct<8; ++ct) {
      int n_local = ct*16 + l15;
      int sc = c ^ (n_local & 7);
      short8 bf = *(const short8*)&Bs[((long)n_local*32 + sc)*8];
      acc[0][ct] = mfma16(a0, bf, acc[0][ct]);
      acc[1][ct] = mfma16(a1, bf, acc[1][ct]);
    }
  }

  #pragma unroll
  for (int ct=0; ct<8; ++ct) {
    int n_g = nt*128 + ct*16 + l15;
    float bv = bias[n_g];
    #pragma unroll
    for (int rt=0; rt<2; ++rt) {
      #pragma unroll
      for (int q=0; q<4; ++q) {
        int r_g = m0 + rt*16 + l4*4 + q;
        if (r_g < M) out[(long)r_g*32000 + n_g] = acc[rt][ct][q] + bv;
      }
    }
  }
}

// ---------------------------------------------------------------------------
extern "C" void kernel_launch(void* const* d_in, const int* in_sizes, int n_in,
                              void* d_out, int out_size, void* d_ws, size_t ws_size,
                              hipStream_t stream)
{
  (void)in_sizes; (void)n_in; (void)out_size; (void)ws_size;
  const int*   ctx_ids  = (const int*)  d_in[0];
  const int*   ctx_mask = (const int*)  d_in[1];
  const float* img      = (const float*)d_in[2];
  const int*   tgt_ids  = (const int*)  d_in[3];
  const float* emb_text = (const float*)d_in[4];
  const float* Wih_t    = (const float*)d_in[5];
  const float* Whh_t    = (const float*)d_in[6];
  const float* bih_t    = (const float*)d_in[7];
  const float* bhh_t    = (const float*)d_in[8];
  const float* fuse_W   = (const float*)d_in[9];
  const float* fuse_b   = (const float*)d_in[10];
  const float* mem_init = (const float*)d_in[11];
  const float* Wih_c    = (const float*)d_in[12];
  const float* Whh_c    = (const float*)d_in[13];
  const float* bih_c    = (const float*)d_in[14];
  const float* bhh_c    = (const float*)d_in[15];
  const float* tok_emb  = (const float*)d_in[16];
  const float* Wih_d    = (const float*)d_in[17];
  const float* Whh_d    = (const float*)d_in[18];
  const float* bih_d    = (const float*)d_in[19];
  const float* bhh_d    = (const float*)d_in[20];
  const float* head_W   = (const float*)d_in[21];
  const float* head_b   = (const float*)d_in[22];
  float* out = (float*)d_out;
  char* ws = (char*)d_ws;

  size_t o = 0;
  auto alloc = [&](size_t bytes){ size_t r = o; o += (bytes + 255) & ~(size_t)255; return r; };
  unsigned short* wWih_t = (unsigned short*)(ws + alloc(768*256*2));
  unsigned short* wWih_c = (unsigned short*)(ws + alloc(768*256*2));
  unsigned short* wWih_d = (unsigned short*)(ws + alloc(768*256*2));
  unsigned short* wFuse  = (unsigned short*)(ws + alloc(256*768*2));
  unsigned char*  wF8_t  = (unsigned char*)(ws + alloc(196608));
  unsigned char*  wF8_c  = (unsigned char*)(ws + alloc(196608));
  unsigned char*  wF8_d  = (unsigned char*)(ws + alloc(196608));
  unsigned short* wHead  = (unsigned short*)(ws + alloc((size_t)32000*256*2));
  unsigned short* ebf    = (unsigned short*)(ws + alloc((size_t)32000*256*2));
  unsigned short* tbf    = (unsigned short*)(ws + alloc((size_t)32000*256*2));
  unsigned short* xg_t   = (unsigned short*)(ws + alloc((size_t)16384*768*2));
  unsigned short* xg_c   = (unsigned short*)(ws + alloc((size_t)512*768*2));
  unsigned short* xg_d   = (unsigned short*)(ws + alloc((size_t)2032*768*2));
  float*          tvec   = (float*)(ws + alloc((size_t)512*256*4));
  float*          zbuf   = (float*)(ws + alloc((size_t)512*256*4));
  float*          z2buf  = (float*)(ws + alloc((size_t)512*256*4));
  unsigned short* outsb  = (unsigned short*)(ws + alloc((size_t)2048*256*2));
  unsigned short* hbdec  = (unsigned short*)(ws + alloc((size_t)16*256*2));

  // 0) weights+tables -> bf16; Whh x3 -> fp8 frag-major
  k_cvt<<<4096, 256, 0, stream>>>(head_W, wHead, emb_text, ebf, tok_emb, tbf,
      Wih_t, Wih_c, Wih_d, fuse_W,
      wWih_t, wWih_c, wWih_d, wFuse);
  k_cvtw<<<288, 256, 0, stream>>>(Whh_t, Whh_c, Whh_d, wF8_t, wF8_c, wF8_d);

  // 1) xg for ctx text GRU (bf16 A table): rows = (b*K+k)*L + l = 16384
  k_gemm<32,32,0,1><<<dim3(256,6), 256, 0, stream>>>(
      ebf, 256, nullptr, 0, 256, ctx_ids, wWih_t, bih_t, 16384, 256, xg_t, 768);

  // 1b) xg for decoder (bf16 A table): rows = b*127 + t = 2032
  k_gemm<127,128,0,1><<<dim3(32,6), 256, 0, stream>>>(
      tbf, 256, nullptr, 0, 256, tgt_ids, wWih_d, bih_d, 2032, 256, xg_d, 768);

  // 2) ctx text GRU (masked), 512 rows / 4 = 128 blocks -> tvec (f32)
  k_gru<<<128, 1024, 0, stream>>>(wF8_t, bhh_t, xg_t, ctx_mask,
                                  nullptr, tvec, nullptr, nullptr, 32);

  // 3) fuse: z = tanh([tvec|img] @ fuse_W^T + fuse_b), 512x256
  k_gemm<1,1,1,0><<<dim3(8,2), 256, 0, stream>>>(
      tvec, 256, img, 512, 256, nullptr, wFuse, fuse_b, 512, 768, zbuf, 256);

  // 4) memory scan -> z2
  k_mem<<<16, 64, 0, stream>>>(zbuf, mem_init, z2buf);

  // 5) xg for ctx GRU2 from z2 (rows b*32+t = 512)
  k_gemm<1,1,0,0><<<dim3(8,6), 256, 0, stream>>>(
      z2buf, 256, nullptr, 0, 256, nullptr, wWih_c, bih_c, 512, 256, xg_c, 768);

  // 6) ctx GRU2: 16 rows / 4 = 4 blocks -> h0 (bf16, global rows)
  k_gru<<<4, 1024, 0, stream>>>(wF8_c, bhh_c, xg_c, nullptr,
                                nullptr, nullptr, hbdec, nullptr, 32);

  // 7) decoder GRU: 16 rows / 4 = 4 blocks, h0 preloaded -> outs bf16
  k_gru<<<4, 1024, 0, stream>>>(wF8_d, bhh_d, xg_d, nullptr,
                                hbdec, nullptr, nullptr, outsb, 127);

  // 8) head: logits
  k_head<<<4000, 256, 0, stream>>>(outsb, wHead, head_b, out, 2032);
}

// Round 23
// 613.824 us; speedup vs baseline: 1.0729x; 1.0729x over previous
//
#include <hip/hip_runtime.h>
#include <hip/hip_bf16.h>

typedef __attribute__((ext_vector_type(4))) float f32x4;
typedef __attribute__((ext_vector_type(8))) short short8;
typedef __attribute__((ext_vector_type(4))) unsigned int u32x4;
typedef __attribute__((ext_vector_type(4))) unsigned short u16x4;
typedef __attribute__((ext_vector_type(8))) int i32x8;

#if __has_builtin(__builtin_amdgcn_mfma_scale_f32_16x16x128_f8f6f4)
#define USE_MX 1
#else
#define USE_MX 0
#endif

static __device__ __forceinline__ unsigned short f2bf(float f){
  unsigned u = __builtin_bit_cast(unsigned, f);
  u += 0x7FFFu + ((u >> 16) & 1u);
  return (unsigned short)(u >> 16);
}
static __device__ __forceinline__ float bf2f(unsigned short b){
  return __builtin_bit_cast(float, ((unsigned)b) << 16);
}
// float -> OCP e4m3fn (software; one-time cvt kernel + fallback)
static __device__ __forceinline__ unsigned char f2e4m3(float x){
  unsigned u = __builtin_bit_cast(unsigned, x);
  unsigned s = (u >> 24) & 0x80u;
  float ax = __builtin_fabsf(x);
  if (ax < 0.015625f) {
    int q = (int)(ax * 512.f + 0.5f);
    return (unsigned char)(s | (unsigned)q);
  }
  if (ax > 448.f) return (unsigned char)(s | 0x7Eu);
  unsigned v = __builtin_bit_cast(unsigned, ax);
  v += 0x00080000u + ((v >> 20) & 1u);
  if (__builtin_bit_cast(float, v & 0xFFF00000u) > 448.f)
    return (unsigned char)(s | 0x7Eu);
  unsigned ee = ((v >> 23) & 0xFFu) - 127u + 7u;
  unsigned m = (v >> 20) & 7u;
  return (unsigned char)(s | (ee << 3) | m);
}
static __device__ __forceinline__ unsigned char h2fp8(float hx16){
#if __has_builtin(__builtin_amdgcn_cvt_pk_fp8_f32)
  int pk = __builtin_amdgcn_cvt_pk_fp8_f32(hx16, hx16, 0, false);
  return (unsigned char)(pk & 0xFF);
#else
  return f2e4m3(hx16);
#endif
}
static __device__ __forceinline__ f32x4 mfma16(short8 a, short8 b, f32x4 c){
  return __builtin_amdgcn_mfma_f32_16x16x32_bf16(a, b, c, 0, 0, 0);
}
static __device__ __forceinline__ f32x4 mfma8(long a, long b, f32x4 c){
  return __builtin_amdgcn_mfma_f32_16x16x32_fp8_fp8(a, b, c, 0, 0, 0);
}
#if USE_MX
// MX fp8 K=128 MFMA, scales = e8m0 127 (x1.0): pure fp8 matmul at 2.25x rate
static __device__ __forceinline__ f32x4 mfma_mx(i32x8 a, i32x8 b, f32x4 c){
  return __builtin_amdgcn_mfma_scale_f32_16x16x128_f8f6f4(
      a, b, c, 0, 0, 0, 127, 0, 127);
}
#endif
static __device__ __forceinline__ float rcpf(float x){ return __builtin_amdgcn_rcpf(x); }
static __device__ __forceinline__ float sigf(float x){ return rcpf(1.f + __expf(-x)); }
static __device__ __forceinline__ float tanhfast(float x){
  float e = __expf(2.f*x);
  return (e - 1.f) * rcpf(e + 1.f);
}
// spread C-fragment: lane (l4,l15) takes component l4 of src-lane l15's vec
static __device__ __forceinline__ float spread4(f32x4 v, int l15, int l4){
  float x0 = __shfl(v[0], l15, 64);
  float x1 = __shfl(v[1], l15, 64);
  float x2 = __shfl(v[2], l15, 64);
  float x3 = __shfl(v[3], l15, 64);
  float s01 = (l4 & 1) ? x1 : x0;
  float s23 = (l4 & 1) ? x3 : x2;
  return (l4 & 2) ? s23 : s01;
}

// ---------------------------------------------------------------------------
// fp32 -> bf16 conversion: head_W + emb_text + tok_emb (big) + 4 smalls.
// ---------------------------------------------------------------------------
__global__ __launch_bounds__(256) void k_cvt(
    const float* __restrict__ sh, unsigned short* __restrict__ dh,
    const float* __restrict__ se, unsigned short* __restrict__ de,
    const float* __restrict__ st, unsigned short* __restrict__ dt,
    const float* __restrict__ s0, const float* __restrict__ s1,
    const float* __restrict__ s2, const float* __restrict__ s3,
    unsigned short* __restrict__ d0, unsigned short* __restrict__ d1,
    unsigned short* __restrict__ d2, unsigned short* __restrict__ d3)
{
  const long NH4 = 2048000;   // 8,192,000 floats / 4 (head, emb, tok each)
  const long NS4 = 49152;     // 196,608 floats / 4
  const long total = 3*NH4 + 4*NS4;
  for (long idx = (long)blockIdx.x*blockDim.x + threadIdx.x; idx < total;
       idx += (long)gridDim.x*blockDim.x) {
    const float* s; unsigned short* d; long off;
    if (idx < NH4)        { s = sh; d = dh; off = idx; }
    else if (idx < 2*NH4) { s = se; d = de; off = idx - NH4; }
    else if (idx < 3*NH4) { s = st; d = dt; off = idx - 2*NH4; }
    else {
      long r = idx - 3*NH4; int mat = (int)(r / NS4); off = r - (long)mat*NS4;
      switch (mat) {
        case 0: s=s0; d=d0; break;  case 1: s=s1; d=d1; break;
        case 2: s=s2; d=d2; break;  default: s=s3; d=d3; break;
      }
    }
    f32x4 v = ((const f32x4*)s)[off];
    u16x4 o2;
    o2[0]=f2bf(v[0]); o2[1]=f2bf(v[1]); o2[2]=f2bf(v[2]); o2[3]=f2bf(v[3]);
    ((u16x4*)d)[off] = o2;
  }
}

// ---------------------------------------------------------------------------
// Whh -> fp8 e4m3 x16 fragment-major.
//   USE_MX: 32B chunk per (w,g,m,lane): row = g*256+w*16+(lane&15),
//           k0 = m*128 + (lane>>4)*32, chunk idx ((w*3+g)*2+m)*64+lane.
//   else  : 8B chunk per (w,g,kb,lane) as in R21/R22.
// ---------------------------------------------------------------------------
__global__ __launch_bounds__(256) void k_cvtw(
    const float* __restrict__ s0, const float* __restrict__ s1,
    const float* __restrict__ s2,
    unsigned char* __restrict__ z0, unsigned char* __restrict__ z1,
    unsigned char* __restrict__ z2)
{
#if USE_MX
  int idx = blockIdx.x*256 + threadIdx.x;     // 3 mats x 6144 32B-chunks
  if (idx >= 3*6144) return;
  int mat = idx / 6144, c = idx % 6144;
  const float* s = (mat==0) ? s0 : (mat==1 ? s1 : s2);
  unsigned char* d = (mat==0) ? z0 : (mat==1 ? z1 : z2);
  int lane = c & 63;
  int rest = c >> 6;          // 0..95
  int m = rest & 1;
  int wg = rest >> 1;         // 0..47
  int g = wg % 3, w = wg / 3;
  int row = g*256 + w*16 + (lane & 15);
  int k0  = m*128 + (lane >> 4)*32;
  const float* sp = s + (long)row*256 + k0;
  #pragma unroll
  for (int h=0; h<2; ++h) {
    u32x4 ov;
    #pragma unroll
    for (int q=0; q<4; ++q) {
      f32x4 a = *(const f32x4*)(sp + h*16 + q*4);
      ov[q] = (unsigned)f2e4m3(a[0]*16.f) | ((unsigned)f2e4m3(a[1]*16.f)<<8) |
              ((unsigned)f2e4m3(a[2]*16.f)<<16) | ((unsigned)f2e4m3(a[3]*16.f)<<24);
    }
    *(u32x4*)(d + (long)c*32 + h*16) = ov;
  }
#else
  int idx = blockIdx.x*256 + threadIdx.x;     // 3 mats x 24576 8B-chunks
  if (idx >= 3*24576) return;
  int mat = idx / 24576, c = idx % 24576;
  const float* s = (mat==0) ? s0 : (mat==1 ? s1 : s2);
  unsigned char* d = (mat==0) ? z0 : (mat==1 ? z1 : z2);
  int lane = c & 63;
  int rest = c >> 6;
  int kb = rest & 7;
  int wg = rest >> 3;
  int g = wg % 3, w = wg / 3;
  int row = g*256 + w*16 + (lane & 15);
  int k0  = kb*32 + (lane >> 4)*8;
  const float* sp = s + (long)row*256 + k0;
  f32x4 a = *(const f32x4*)sp;
  f32x4 b = *(const f32x4*)(sp + 4);
  unsigned lo = (unsigned)f2e4m3(a[0]*16.f) | ((unsigned)f2e4m3(a[1]*16.f)<<8) |
                ((unsigned)f2e4m3(a[2]*16.f)<<16) | ((unsigned)f2e4m3(a[3]*16.f)<<24);
  unsigned hi = (unsigned)f2e4m3(b[0]*16.f) | ((unsigned)f2e4m3(b[1]*16.f)<<8) |
                ((unsigned)f2e4m3(b[2]*16.f)<<16) | ((unsigned)f2e4m3(b[3]*16.f)<<24);
  *(unsigned*)(d + (long)c*8)     = lo;
  *(unsigned*)(d + (long)c*8 + 4) = hi;
#endif
}

// ---------------------------------------------------------------------------
// Generic MFMA GEMM: out[M][N] = gatherA[M][Ktot] @ W[N][Ktot]^T + bias
//   AT=0: fp32 A table (with optional concat tabB2); AT=1: bf16 A table.
// ---------------------------------------------------------------------------
template<int TN, int TS, int EPI, int AT>
__global__ __launch_bounds__(256) void k_gemm(
    const void* __restrict__ tabA_, int ldA,
    const float* __restrict__ tabB2, int ldB2, int K1,
    const int* __restrict__ ids,
    const unsigned short* __restrict__ W,   // [N][Ktot] bf16
    const float* __restrict__ bias,         // [N]
    int M, int Ktot,
    void* __restrict__ outp, int ldOut)
{
  const int bm = blockIdx.x, bn = blockIdx.y;
  const int tid = threadIdx.x;
  const int lane = tid & 63, w = tid >> 6;
  const int l15 = lane & 15, l4 = lane >> 4;

  const int r_g = bm*64 + w*16 + l15;
  const int r_c = (r_g < M) ? r_g : (M-1);
  long row_src;
  if (ids) { int ii = (r_c / TN) * TS + (r_c % TN); row_src = ids[ii]; }
  else row_src = r_c;

  const int kchunk = l4 * 8;
  const int ncol0 = bn*128 + l15;

  f32x4 acc[8];
  #pragma unroll
  for (int i=0;i<8;i++){ f32x4 z4 = {0.f,0.f,0.f,0.f}; acc[i]=z4; }

  const int KB = Ktot >> 5;
  for (int kb = 0; kb < KB; ++kb) {
    int k = kb*32 + kchunk;
    short8 afr;
    if (AT == 1) {
      afr = *(const short8*)((const unsigned short*)tabA_ + row_src*(long)ldA + k);
    } else {
      const float* ap;
      if (tabB2 && k >= K1) ap = tabB2 + row_src*(long)ldB2 + (k - K1);
      else                  ap = (const float*)tabA_ + row_src*(long)ldA + k;
      f32x4 a0 = *(const f32x4*)ap;
      f32x4 a1 = *(const f32x4*)(ap + 4);
      afr[0]=(short)f2bf(a0[0]); afr[1]=(short)f2bf(a0[1]);
      afr[2]=(short)f2bf(a0[2]); afr[3]=(short)f2bf(a0[3]);
      afr[4]=(short)f2bf(a1[0]); afr[5]=(short)f2bf(a1[1]);
      afr[6]=(short)f2bf(a1[2]); afr[7]=(short)f2bf(a1[3]);
    }
    #pragma unroll
    for (int ct=0; ct<8; ++ct) {
      int n = ncol0 + ct*16;
      short8 bfr = *(const short8*)(W + (long)n*Ktot + k);
      acc[ct] = mfma16(afr, bfr, acc[ct]);
    }
  }

  #pragma unroll
  for (int ct=0; ct<8; ++ct) {
    int n = ncol0 + ct*16;
    float bv = bias[n];
    #pragma unroll
    for (int q=0; q<4; ++q) {
      int rr = bm*64 + w*16 + l4*4 + q;
      if (rr < M) {
        float v = acc[ct][q] + bv;
        if (EPI == 1) ((float*)outp)[(long)rr*ldOut + n] = tanhfast(v);
        else ((unsigned short*)outp)[(long)rr*ldOut + n] = f2bf(v);
      }
    }
  }
}

// ---------------------------------------------------------------------------
// GRU recurrence, ROW-SPLIT (4 rows/block) + SHUFFLE-SPREAD + ALL-FP8 + MX.
//   R21/R22 = 175us decoder (3310cy/step), MFMA floor ~1890cy at the
//   K=32 fp8 (=bf16) rate. MX K=128 fp8 runs 2.25x faster (m21: 4661 TF)
//   and cuts MFMA count 24->6 per wave per step -> floor ~830cy.
//   Scales = e8m0 127 (x1.0): identical products to the K=32 path.
//   A/B lane mapping: k = (lane>>4)*32 + [0..31] (+m*128); C/D layout is
//   shape-determined (guide-verified) so spread4 is unchanged.
//   h8z stride 272 (16B-aligned 32B reads). Fallback: R22 K=32 path.
// ---------------------------------------------------------------------------
__global__ __launch_bounds__(1024, 1) void k_gru(
    const unsigned char*  __restrict__ WF8,  // fp8 frag-major (k_cvtw)
    const float* __restrict__ bhh,           // [768]
    const unsigned short* __restrict__ xg,   // [(grow*T+t)][768] bf16 (bih inc.)
    const int* __restrict__ mask,            // [(grow*T+t)] or null
    const unsigned short* __restrict__ h0bf, // [16][256] bf16 GLOBAL rows, or null
    float* __restrict__ hNf,                 // [grow][256] f32 or null
    unsigned short* __restrict__ hNbf,       // [16][256] bf16 GLOBAL rows, or null
    unsigned short* __restrict__ outs,       // [(grow*T+t)][256] bf16 or null
    int T)
{
#if USE_MX
  __shared__ unsigned char h8z[9*272];       // stride 272: 16B-aligned 32B reads
  const int HS = 272;
#else
  __shared__ unsigned char h8z[9*264];
  const int HS = 264;
#endif

  const int tid = threadIdx.x;
  const int w = tid >> 6, lane = tid & 63;
  const int l15 = lane & 15, l4 = lane >> 4;
  const int rowbase = blockIdx.x * 4;
  const int u = w*16 + l15;                  // this lane's unit
  const int gr = l4;                         // this lane's gate row (0..3)

#if USE_MX
  // ---- weights: 3 gates x 2 k-halves of i32x8 = 48 VGPR ----
  i32x8 Bmx[3][2];
  #pragma unroll
  for (int g=0; g<3; ++g)
    #pragma unroll
    for (int m=0; m<2; ++m)
      Bmx[g][m] = *(const i32x8*)(WF8 + ((long)((w*3+g)*2+m)*64 + lane)*32);
#else
  long Bf8[3][8];
  #pragma unroll
  for (int g=0; g<3; ++g)
    #pragma unroll
    for (int kb=0; kb<8; ++kb)
      Bf8[g][kb] = *(const long*)(WF8 + ((long)((w*3+g)*8+kb)*512) + lane*8);
#endif

  const float b_r = bhh[u], b_z = bhh[256+u], b_n = bhh[512+u];

  // A-read offsets (parity-selected; tile rows >=4 alias zero-row 8)
  const int arow0 = (l15 < 4) ? l15     : 8;
  const int arow1 = (l15 < 4) ? 4 + l15 : 8;
#if USE_MX
  const int h8O0 = arow0*HS + l4*32;
  const int h8O1 = arow1*HS + l4*32;
#else
  const int h8O0 = arow0*HS + l4*8;
  const int h8O1 = arow1*HS + l4*8;
#endif
  // parity-selected h write offsets (p=0 writes rows 4-7; p=1 rows 0-3)
  const int wA0 = (4+gr)*HS + u;
  const int wA1 = gr*HS + u;

  // ---- hoisted per-step pointers (this lane's row = rowbase+gr) ----
  const long row0 = (long)(rowbase + gr)*T;
  const unsigned short* xp = xg + row0*768 + u;
  unsigned short* op = outs ? (outs + row0*256 + u) : (unsigned short*)0;
  const int* mp = mask ? (mask + row0) : (const int*)0;

  // ---- init: zero row 8; lane owns (row gr, unit u); exact f32 h ----
  if (tid < HS) h8z[8*HS + tid] = 0;
  float h = h0bf ? bf2f(h0bf[(rowbase+gr)*256 + u]) : 0.f;
  h8z[gr*HS + u] = h2fp8(h * 16.f);
  __syncthreads();

  const float inv256 = 0.00390625f;

  for (int t=0; t<T; ++t) {
    const int p = t & 1;

    const unsigned short xr_ = xp[0];
    const unsigned short xz_ = xp[256];
    const unsigned short xn_ = xp[512];
    const int mok = mp ? *mp : 1;

    const int h8O = p ? h8O1 : h8O0;
    f32x4 aR={0.f,0.f,0.f,0.f}, aZ={0.f,0.f,0.f,0.f}, aN={0.f,0.f,0.f,0.f};
#if USE_MX
    {
      i32x8 a80 = *(const i32x8*)&h8z[h8O];
      i32x8 a81 = *(const i32x8*)&h8z[h8O + 128];
      aR = mfma_mx(a80, Bmx[0][0], aR);
      aZ = mfma_mx(a80, Bmx[1][0], aZ);
      aN = mfma_mx(a80, Bmx[2][0], aN);
      aR = mfma_mx(a81, Bmx[0][1], aR);
      aZ = mfma_mx(a81, Bmx[1][1], aZ);
      aN = mfma_mx(a81, Bmx[2][1], aN);
    }
#else
    #pragma unroll
    for (int kb=0; kb<8; ++kb) {
      long a8 = *(const long*)&h8z[h8O + kb*32];
      aR = mfma8(a8, Bf8[0][kb], aR);
      aZ = mfma8(a8, Bf8[1][kb], aZ);
      aN = mfma8(a8, Bf8[2][kb], aN);
    }
#endif

    // ---- spread C rows across the wave; ONE gate triple per lane ----
    float gR = spread4(aR, l15, l4) * inv256;
    float gZ = spread4(aZ, l15, l4) * inv256;
    float gN = spread4(aN, l15, l4) * inv256;

    float rr = sigf(bf2f(xr_) + gR + b_r);
    float zz = sigf(bf2f(xz_) + gZ + b_z);
    float nn = tanhfast(bf2f(xn_) + rr*(gN + b_n));
    float hv = nn + zz*(h - nn);
    if (!mok) hv = h;
    h = hv;
    h8z[p ? wA1 : wA0] = h2fp8(hv * 16.f);
    if (op) { *op = f2bf(hv); op += 256; }
    xp += 768;
    if (mp) ++mp;
    __syncthreads();
  }

  if (hNf)  hNf[(long)(rowbase+gr)*256 + u] = h;
  if (hNbf) hNbf[(rowbase+gr)*256 + u] = f2bf(h);
}

// ---------------------------------------------------------------------------
// Memory scan: per batch b (block, 1 wave): 32 steps of attention-write memory.
// ---------------------------------------------------------------------------
__global__ __launch_bounds__(64) void k_mem(
    const float* __restrict__ z,         // [512][256] rows b*32+t
    const float* __restrict__ mem_init,  // [16][256]
    float* __restrict__ z2)              // [512][256]
{
  const int b = blockIdx.x;
  const int lane = threadIdx.x;
  float mem[16][4];
  #pragma unroll
  for (int m=0; m<16; ++m) {
    f32x4 v = *(const f32x4*)(mem_init + m*256 + lane*4);
    mem[m][0]=v[0]; mem[m][1]=v[1]; mem[m][2]=v[2]; mem[m][3]=v[3];
  }
  for (int t=0; t<32; ++t) {
    f32x4 q = *(const f32x4*)(z + ((long)b*32 + t)*256 + lane*4);
    float s[16];
    #pragma unroll
    for (int m=0; m<16; ++m)
      s[m] = mem[m][0]*q[0] + mem[m][1]*q[1] + mem[m][2]*q[2] + mem[m][3]*q[3];
    #pragma unroll
    for (int st=1; st<64; st<<=1) {
      #pragma unroll
      for (int m=0; m<16; ++m) s[m] += __shfl_xor(s[m], st, 64);
    }
    float mx = -1e30f;
    #pragma unroll
    for (int m=0; m<16; ++m) { s[m] *= 0.0625f; mx = fmaxf(mx, s[m]); }
    float sum = 0.f;
    #pragma unroll
    for (int m=0; m<16; ++m) { s[m] = __expf(s[m]-mx); sum += s[m]; }
    float inv = rcpf(sum);
    f32x4 ro = {0.f,0.f,0.f,0.f};
    #pragma unroll
    for (int m=0; m<16; ++m) {
      float wm = s[m]*inv;
      #pragma unroll
      for (int c=0; c<4; ++c) {
        ro[c] += wm * mem[m][c];
        mem[m][c] += wm * (q[c] - mem[m][c]);
      }
    }
    f32x4 o = q + ro;
    *(f32x4*)(z2 + ((long)b*32 + t)*256 + lane*4) = o;
  }
}

// ---------------------------------------------------------------------------
// Head GEMM: out[2032][32000] = A[2032][256]bf16 @ Bw[32000][256]^T + bias
// ---------------------------------------------------------------------------
__global__ __launch_bounds__(256) void k_head(
    const unsigned short* __restrict__ A,    // [2048][256] bf16 (padded)
    const unsigned short* __restrict__ Bw,   // [32000][256] bf16
    const float* __restrict__ bias,          // [32000]
    float* __restrict__ out,                 // [2032][32000]
    int M)
{
  __shared__ unsigned short Bs[32768];       // 64 KB
  const int bid = blockIdx.x;
  const int mt = bid % 16, nt = bid / 16;
  const int tid = threadIdx.x;
  const int lane = tid & 63, w = tid >> 6;
  const int l15 = lane & 15, l4 = lane >> 4;

  const long nbase = (long)nt * 128;
  #pragma unroll
  for (int it=0; it<16; ++it) {
    int idx = it*256 + tid;
    int rr = idx >> 5;
    int ch = idx & 31;
    int sch = ch ^ (rr & 7);
    u32x4 v = *(const u32x4*)(Bw + (nbase+rr)*256 + sch*8);
    *(u32x4*)&Bs[(long)idx*8] = v;
  }
  __syncthreads();

  const int m0 = mt*128 + w*32;
  const int arow0 = m0 + l15, arow1 = arow0 + 16;
  const int kc = l4 * 8;

  f32x4 acc[2][8];
  #pragma unroll
  for (int rt=0; rt<2; ++rt)
    #pragma unroll
    for (int ct=0; ct<8; ++ct){ f32x4 z4={0.f,0.f,0.f,0.f}; acc[rt][ct]=z4; }

  #pragma unroll
  for (int kb=0; kb<8; ++kb) {
    short8 a0 = *(const short8*)(A + (long)arow0*256 + kb*32 + kc);
    short8 a1 = *(const short8*)(A + (long)arow1*256 + kb*32 + kc);
    int c = kb*4 + l4;
    #pragma unroll
    for (int ct=0; ct<8; ++ct) {
      int n_local = ct*16 + l15;
      int sc = c ^ (n_local & 7);
      short8 bf = *(const short8*)&Bs[((long)n_local*32 + sc)*8];
      acc[0][ct] = mfma16(a0, bf, acc[0][ct]);
      acc[1][ct] = mfma16(a1, bf, acc[1][ct]);
    }
  }

  #pragma unroll
  for (int ct=0; ct<8; ++ct) {
    int n_g = nt*128 + ct*16 + l15;
    float bv = bias[n_g];
    #pragma unroll
    for (int rt=0; rt<2; ++rt) {
      #pragma unroll
      for (int q=0; q<4; ++q) {
        int r_g = m0 + rt*16 + l4*4 + q;
        if (r_g < M) out[(long)r_g*32000 + n_g] = acc[rt][ct][q] + bv;
      }
    }
  }
}

// ---------------------------------------------------------------------------
extern "C" void kernel_launch(void* const* d_in, const int* in_sizes, int n_in,
                              void* d_out, int out_size, void* d_ws, size_t ws_size,
                              hipStream_t stream)
{
  (void)in_sizes; (void)n_in; (void)out_size; (void)ws_size;
  const int*   ctx_ids  = (const int*)  d_in[0];
  const int*   ctx_mask = (const int*)  d_in[1];
  const float* img      = (const float*)d_in[2];
  const int*   tgt_ids  = (const int*)  d_in[3];
  const float* emb_text = (const float*)d_in[4];
  const float* Wih_t    = (const float*)d_in[5];
  const float* Whh_t    = (const float*)d_in[6];
  const float* bih_t    = (const float*)d_in[7];
  const float* bhh_t    = (const float*)d_in[8];
  const float* fuse_W   = (const float*)d_in[9];
  const float* fuse_b   = (const float*)d_in[10];
  const float* mem_init = (const float*)d_in[11];
  const float* Wih_c    = (const float*)d_in[12];
  const float* Whh_c    = (const float*)d_in[13];
  const float* bih_c    = (const float*)d_in[14];
  const float* bhh_c    = (const float*)d_in[15];
  const float* tok_emb  = (const float*)d_in[16];
  const float* Wih_d    = (const float*)d_in[17];
  const float* Whh_d    = (const float*)d_in[18];
  const float* bih_d    = (const float*)d_in[19];
  const float* bhh_d    = (const float*)d_in[20];
  const float* head_W   = (const float*)d_in[21];
  const float* head_b   = (const float*)d_in[22];
  float* out = (float*)d_out;
  char* ws = (char*)d_ws;

  size_t o = 0;
  auto alloc = [&](size_t bytes){ size_t r = o; o += (bytes + 255) & ~(size_t)255; return r; };
  unsigned short* wWih_t = (unsigned short*)(ws + alloc(768*256*2));
  unsigned short* wWih_c = (unsigned short*)(ws + alloc(768*256*2));
  unsigned short* wWih_d = (unsigned short*)(ws + alloc(768*256*2));
  unsigned short* wFuse  = (unsigned short*)(ws + alloc(256*768*2));
  unsigned char*  wF8_t  = (unsigned char*)(ws + alloc(196608));
  unsigned char*  wF8_c  = (unsigned char*)(ws + alloc(196608));
  unsigned char*  wF8_d  = (unsigned char*)(ws + alloc(196608));
  unsigned short* wHead  = (unsigned short*)(ws + alloc((size_t)32000*256*2));
  unsigned short* ebf    = (unsigned short*)(ws + alloc((size_t)32000*256*2));
  unsigned short* tbf    = (unsigned short*)(ws + alloc((size_t)32000*256*2));
  unsigned short* xg_t   = (unsigned short*)(ws + alloc((size_t)16384*768*2));
  unsigned short* xg_c   = (unsigned short*)(ws + alloc((size_t)512*768*2));
  unsigned short* xg_d   = (unsigned short*)(ws + alloc((size_t)2032*768*2));
  float*          tvec   = (float*)(ws + alloc((size_t)512*256*4));
  float*          zbuf   = (float*)(ws + alloc((size_t)512*256*4));
  float*          z2buf  = (float*)(ws + alloc((size_t)512*256*4));
  unsigned short* outsb  = (unsigned short*)(ws + alloc((size_t)2048*256*2));
  unsigned short* hbdec  = (unsigned short*)(ws + alloc((size_t)16*256*2));

  // 0) weights+tables -> bf16; Whh x3 -> fp8 frag-major (MX or K32 layout)
  k_cvt<<<4096, 256, 0, stream>>>(head_W, wHead, emb_text, ebf, tok_emb, tbf,
      Wih_t, Wih_c, Wih_d, fuse_W,
      wWih_t, wWih_c, wWih_d, wFuse);
  k_cvtw<<<288, 256, 0, stream>>>(Whh_t, Whh_c, Whh_d, wF8_t, wF8_c, wF8_d);

  // 1) xg for ctx text GRU (bf16 A table): rows = (b*K+k)*L + l = 16384
  k_gemm<32,32,0,1><<<dim3(256,6), 256, 0, stream>>>(
      ebf, 256, nullptr, 0, 256, ctx_ids, wWih_t, bih_t, 16384, 256, xg_t, 768);

  // 1b) xg for decoder (bf16 A table): rows = b*127 + t = 2032
  k_gemm<127,128,0,1><<<dim3(32,6), 256, 0, stream>>>(
      tbf, 256, nullptr, 0, 256, tgt_ids, wWih_d, bih_d, 2032, 256, xg_d, 768);

  // 2) ctx text GRU (masked), 512 rows / 4 = 128 blocks -> tvec (f32)
  k_gru<<<128, 1024, 0, stream>>>(wF8_t, bhh_t, xg_t, ctx_mask,
                                  nullptr, tvec, nullptr, nullptr, 32);

  // 3) fuse: z = tanh([tvec|img] @ fuse_W^T + fuse_b), 512x256
  k_gemm<1,1,1,0><<<dim3(8,2), 256, 0, stream>>>(
      tvec, 256, img, 512, 256, nullptr, wFuse, fuse_b, 512, 768, zbuf, 256);

  // 4) memory scan -> z2
  k_mem<<<16, 64, 0, stream>>>(zbuf, mem_init, z2buf);

  // 5) xg for ctx GRU2 from z2 (rows b*32+t = 512)
  k_gemm<1,1,0,0><<<dim3(8,6), 256, 0, stream>>>(
      z2buf, 256, nullptr, 0, 256, nullptr, wWih_c, bih_c, 512, 256, xg_c, 768);

  // 6) ctx GRU2: 16 rows / 4 = 4 blocks -> h0 (bf16, global rows)
  k_gru<<<4, 1024, 0, stream>>>(wF8_c, bhh_c, xg_c, nullptr,
                                nullptr, nullptr, hbdec, nullptr, 32);

  // 7) decoder GRU: 16 rows / 4 = 4 blocks, h0 preloaded -> outs bf16
  k_gru<<<4, 1024, 0, stream>>>(wF8_d, bhh_d, xg_d, nullptr,
                                hbdec, nullptr, nullptr, outsb, 127);

  // 8) head: logits
  k_head<<<4000, 256, 0, stream>>>(outsb, wHead, head_b, out, 2032);
}